// Round 4
// baseline (1016.614 us; speedup 1.0000x reference)
//
#include <hip/hip_runtime.h>

typedef unsigned short ushort_t;
typedef __bf16 bf16x8 __attribute__((ext_vector_type(8)));
typedef float floatx4 __attribute__((ext_vector_type(4)));
typedef unsigned short ushort8 __attribute__((ext_vector_type(8)));

#define BM 128
#define BN 128
#define BKK 64

__device__ __forceinline__ ushort_t f2bf(float f) {
  union { float f; unsigned int u; } c; c.f = f;
  unsigned int r = c.u + 0x7FFFu + ((c.u >> 16) & 1u);
  return (ushort_t)(r >> 16);
}

// C[M,N] = A[M,K] (row-major bf16) x Bt[N,K] (row-major bf16), fp32 accum.
// BIASM: 0 none, 1 bias[m], 2 bias[n]  (bias is fp32)
// POOLM: 0 none, 1 maxpool pairs along n (shfl, write n/2, ldc=N/2),
//        2 maxpool pairs along m (register pairs, write m/2)
// OUTF32: write float instead of bf16.
template<int BIASM, int POOLM, bool OUTF32>
__global__ __launch_bounds__(256)
void gemm_bt(const ushort_t* __restrict__ A, long aStr,
             const ushort_t* __restrict__ B, long bStr,
             void* __restrict__ Cp, long cStr,
             int K, int lda, int ldb, int ldc,
             const float* __restrict__ bias, float scale)
{
  __shared__ ushort_t As[BM][BKK];
  __shared__ ushort_t Bs[BN][BKK];
  A += (long)blockIdx.z * aStr;
  B += (long)blockIdx.z * bStr;
  float* Cf = (float*)Cp + (OUTF32 ? (long)blockIdx.z * cStr : 0);
  ushort_t* Cb = (ushort_t*)Cp + (OUTF32 ? 0 : (long)blockIdx.z * cStr);
  const int m0 = blockIdx.y * BM;
  const int n0 = blockIdx.x * BN;
  const int tid = threadIdx.x;
  const int lane = tid & 63;
  const int wm = (tid >> 7) & 1;
  const int wn = (tid >> 6) & 1;
  const int ar = tid >> 3;         // staging row 0..31
  const int ac = (tid & 7) * 8;    // staging col (8 bf16 per thread)

  floatx4 acc[4][4];
#pragma unroll
  for (int i = 0; i < 4; ++i)
#pragma unroll
    for (int j = 0; j < 4; ++j)
#pragma unroll
      for (int r = 0; r < 4; ++r) acc[i][j][r] = 0.0f;

  const int q8 = (lane >> 4) * 8;
  const int l15 = lane & 15;

  for (int k0 = 0; k0 < K; k0 += BKK) {
#pragma unroll
    for (int p = 0; p < 4; ++p) {
      int row = p * 32 + ar;
      *(ushort8*)(&As[row][ac]) = *(const ushort8*)(&A[(long)(m0 + row) * lda + k0 + ac]);
      *(ushort8*)(&Bs[row][ac]) = *(const ushort8*)(&B[(long)(n0 + row) * ldb + k0 + ac]);
    }
    __syncthreads();
#pragma unroll
    for (int kk = 0; kk < 2; ++kk) {
      const int kr = kk * 32 + q8;
      bf16x8 af[4], bfr[4];
#pragma unroll
      for (int i = 0; i < 4; ++i) {
        af[i]  = *(const bf16x8*)(&As[wm * 64 + i * 16 + l15][kr]);
        bfr[i] = *(const bf16x8*)(&Bs[wn * 64 + i * 16 + l15][kr]);
      }
#pragma unroll
      for (int i = 0; i < 4; ++i)
#pragma unroll
        for (int j = 0; j < 4; ++j)
          acc[i][j] = __builtin_amdgcn_mfma_f32_16x16x32_bf16(af[i], bfr[j], acc[i][j], 0, 0, 0);
    }
    __syncthreads();
  }

#pragma unroll
  for (int i = 0; i < 4; ++i) {
    const int mbase = m0 + wm * 64 + i * 16 + (lane >> 4) * 4;
#pragma unroll
    for (int j = 0; j < 4; ++j) {
      const int n = n0 + wn * 64 + j * 16 + l15;
      float v[4];
#pragma unroll
      for (int r = 0; r < 4; ++r) {
        v[r] = acc[i][j][r] * scale;
        if (BIASM == 1) v[r] += bias[mbase + r];
      }
      if (BIASM == 2) {
        const float bn_ = bias[n];
#pragma unroll
        for (int r = 0; r < 4; ++r) v[r] += bn_;
      }
      if (POOLM == 0) {
#pragma unroll
        for (int r = 0; r < 4; ++r) {
          if (OUTF32) Cf[(long)(mbase + r) * ldc + n] = v[r];
          else        Cb[(long)(mbase + r) * ldc + n] = f2bf(v[r]);
        }
      } else if (POOLM == 1) {
#pragma unroll
        for (int r = 0; r < 4; ++r) {
          float o = __shfl_xor(v[r], 1);
          float w = fmaxf(v[r], o);
          if ((lane & 1) == 0) {
            if (OUTF32) Cf[(long)(mbase + r) * ldc + (n >> 1)] = w;
            else        Cb[(long)(mbase + r) * ldc + (n >> 1)] = f2bf(w);
          }
        }
      } else {  // POOLM == 2
        float w0 = fmaxf(v[0], v[1]);
        float w1 = fmaxf(v[2], v[3]);
        const int mh = mbase >> 1;
        if (OUTF32) {
          Cf[(long)mh * ldc + n] = w0;
          Cf[(long)(mh + 1) * ldc + n] = w1;
        } else {
          Cb[(long)mh * ldc + n] = f2bf(w0);
          Cb[(long)(mh + 1) * ldc + n] = f2bf(w1);
        }
      }
    }
  }
}

// dst[t][c] = bf16(src[c][t]) per batch. src: (Rr, Cl) fp32 row-major.
__global__ __launch_bounds__(256)
void transpose_f32_bf16(const float* __restrict__ src, ushort_t* __restrict__ dst,
                        int Rr, int Cl)
{
  __shared__ ushort_t tile[32][33];
  const long boff = (long)blockIdx.z * Rr * Cl;
  const int tx = threadIdx.x & 31;
  const int ty = threadIdx.x >> 5;
  const int c0 = blockIdx.x * 32;
  const int r0 = blockIdx.y * 32;
#pragma unroll
  for (int i = 0; i < 4; ++i) {
    int r = ty + i * 8;
    tile[r][tx] = f2bf(src[boff + (long)(r0 + r) * Cl + c0 + tx]);
  }
  __syncthreads();
#pragma unroll
  for (int i = 0; i < 4; ++i) {
    int r = ty + i * 8;
    dst[boff + (long)(c0 + r) * Rr + r0 + tx] = tile[tx][r];
  }
}

// Convert 4 equal-size fp32 weight buffers to contiguous bf16 regions.
__global__ __launch_bounds__(256)
void convert4(const float* __restrict__ a, const float* __restrict__ b,
              const float* __restrict__ c, const float* __restrict__ d,
              ushort_t* __restrict__ dst, int n)
{
  const float* srcs[4] = {a, b, c, d};
  const float* s = srcs[blockIdx.y];
  int i = blockIdx.x * 256 + threadIdx.x;
  if (i < n) dst[(long)blockIdx.y * n + i] = f2bf(s[i]);
}

// One block per channel c: mean/rstd over (B,T) of y (B,C,T) fp32.
__global__ __launch_bounds__(256)
void bn_stats(const float* __restrict__ y, float* __restrict__ stats)
{
  const int c = blockIdx.x;
  float s = 0.0f, s2 = 0.0f;
  for (int b = 0; b < 16; ++b) {
    const float* row = y + ((long)b * 1024 + c) * 2048;
    for (int t = threadIdx.x; t < 2048; t += 256) {
      float v = row[t];
      s += v; s2 += v * v;
    }
  }
#pragma unroll
  for (int o = 32; o > 0; o >>= 1) { s += __shfl_down(s, o); s2 += __shfl_down(s2, o); }
  __shared__ float red[8];
  const int lane = threadIdx.x & 63, w = threadIdx.x >> 6;
  if (lane == 0) { red[w] = s; red[4 + w] = s2; }
  __syncthreads();
  if (threadIdx.x == 0) {
    s = red[0] + red[1] + red[2] + red[3];
    s2 = red[4] + red[5] + red[6] + red[7];
    const float inv = 1.0f / (16.0f * 2048.0f);
    float mean = s * inv;
    float var = s2 * inv - mean * mean;
    stats[c * 2] = mean;
    stats[c * 2 + 1] = rsqrtf(var + 1e-5f);
  }
}

// In-place: y = gamma*(y-mean)*rstd + beta + x ; one block per (b,c) row.
__global__ __launch_bounds__(256)
void bn_apply(float* __restrict__ y, const float* __restrict__ x,
              const float* __restrict__ stats, const float* __restrict__ gamma,
              const float* __restrict__ beta)
{
  const int bc = blockIdx.x;
  const int c = bc & 1023;
  const long off = (long)bc * 2048;
  const float mean = stats[c * 2], rstd = stats[c * 2 + 1];
  const float g = gamma[c] * rstd;
  const float bt = beta[c];
  for (int t = threadIdx.x; t < 2048; t += 256) {
    y[off + t] = (y[off + t] - mean) * g + bt + x[off + t];
  }
}

extern "C" void kernel_launch(void* const* d_in, const int* in_sizes, int n_in,
                              void* d_out, int out_size, void* d_ws, size_t ws_size,
                              hipStream_t stream) {
  (void)in_sizes; (void)n_in; (void)out_size; (void)ws_size;
  const float* x  = (const float*)d_in[0];
  const float* Wq = (const float*)d_in[1];
  const float* bq = (const float*)d_in[2];
  const float* Wk = (const float*)d_in[3];
  const float* bk = (const float*)d_in[4];
  const float* Wv = (const float*)d_in[5];
  const float* bv = (const float*)d_in[6];
  const float* Wo = (const float*)d_in[7];
  const float* bo = (const float*)d_in[8];
  const float* gamma = (const float*)d_in[9];
  const float* beta  = (const float*)d_in[10];
  float* out = (float*)d_out;

  const int Cc = 1024, T = 2048, D = 512, S = 1024;

  // Workspace (bf16 elems), peak ~88 MiB:
  //   Qt  [0, 16M)        : (B,T,D) — becomes out2 (same shape) per batch pair
  //   Kt  [16M, 25.2M)    : (B,S,D)
  //   V   [25.2M, 33.6M)  : (B,D,S)
  //   xT  [33.6M, 41.9M)  : 4-batch groups (T,C) — later aliased by attn (2 batches)
  //   W*  [41.9M, 44.0M)  : bf16 weights
  //   stats at 44.04M (fp32, 2048 floats)
  ushort_t* ws   = (ushort_t*)d_ws;
  ushort_t* Qt   = ws;                 // 16,777,216
  ushort_t* Kt   = ws + 16777216;      //  8,388,608
  ushort_t* V    = ws + 25165824;      //  8,388,608
  ushort_t* xT   = ws + 33554432;      //  8,388,608 (4 batches x T x C)
  ushort_t* attn = ws + 33554432;      // alias xT: 2 batches x T x S = 4,194,304
  ushort_t* Wq_b = ws + 41943040;      //    524,288
  ushort_t* Wk_b = ws + 42467328;
  ushort_t* Wv_b = ws + 42991616;
  ushort_t* Wo_b = ws + 43515904;
  float*    stats = (float*)(ws + 44040192);

  dim3 blk(256);

  // 0. Weights fp32 -> bf16.
  convert4<<<dim3(2048, 4), blk, 0, stream>>>(Wq, Wk, Wv, Wo, Wq_b, D * Cc);

  // 1. Per 4-batch group: xT = bf16(x^T); Qt, Kt (time-pooled), V (time-pooled).
  for (int g = 0; g < 4; ++g) {
    const float* xg = x + (long)g * 4 * Cc * T;
    transpose_f32_bf16<<<dim3(T / 32, Cc / 32, 4), blk, 0, stream>>>(xg, xT, Cc, T);
    // Qt (T,D): M=T, N=D, K=C; A=xT, B=Wq_b, bias bq by n.
    gemm_bt<2, 0, false><<<dim3(D / BN, T / BM, 4), blk, 0, stream>>>(
        xT, (long)T * Cc, Wq_b, 0, Qt + (long)g * 4 * T * D, (long)T * D,
        Cc, Cc, Cc, D, bq, 1.0f);
    // Kt (S,D): same GEMM, maxpool over time pairs (m), bias bk by n.
    gemm_bt<2, 2, false><<<dim3(D / BN, T / BM, 4), blk, 0, stream>>>(
        xT, (long)T * Cc, Wk_b, 0, Kt + (long)g * 4 * S * D, (long)S * D,
        Cc, Cc, Cc, D, bk, 1.0f);
    // V (D,S): M=D, N=T, K=C; A=Wv_b, B=xT, maxpool over time pairs (n), bias bv by m.
    gemm_bt<1, 1, false><<<dim3(T / BN, D / BM, 4), blk, 0, stream>>>(
        Wv_b, 0, xT, (long)T * Cc, V + (long)g * 4 * D * S, (long)D * S,
        Cc, Cc, Cc, S, bv, 1.0f);
  }

  // 2. Attention per 2-batch pair: attn = (Qt x Kt^T)/T ; out2 = attn x V^T (over Qt).
  for (int p = 0; p < 8; ++p) {
    gemm_bt<0, 0, false><<<dim3(S / BN, T / BM, 2), blk, 0, stream>>>(
        Qt + (long)p * 2 * T * D, (long)T * D,
        Kt + (long)p * 2 * S * D, (long)S * D,
        attn, (long)T * S, D, D, D, S, nullptr, 1.0f / 2048.0f);
    gemm_bt<0, 0, false><<<dim3(D / BN, T / BM, 2), blk, 0, stream>>>(
        attn, (long)T * S,
        V + (long)p * 2 * D * S, (long)D * S,
        Qt + (long)p * 2 * T * D, (long)T * D, S, S, S, D, nullptr, 1.0f);
  }

  // 3. y = Wo x out2^T + bo -> d_out (fp32, (B,C,T)).
  gemm_bt<1, 0, true><<<dim3(T / BN, Cc / BM, 16), blk, 0, stream>>>(
      Wo_b, 0, Qt, (long)T * D, out, (long)Cc * T, D, D, D, T, bo, 1.0f);

  // 4. BatchNorm (training stats, biased var) + residual, in place on d_out.
  bn_stats<<<dim3(1024), blk, 0, stream>>>(out, stats);
  bn_apply<<<dim3(16384), blk, 0, stream>>>(out, x, stats, gamma, beta);
}

// Round 5
// 714.726 us; speedup vs baseline: 1.4224x; 1.4224x over previous
//
#include <hip/hip_runtime.h>

typedef unsigned short ushort_t;
typedef __bf16 bf16x8 __attribute__((ext_vector_type(8)));
typedef float floatx4 __attribute__((ext_vector_type(4)));

#define BM 128
#define BN 128
#define BKK 64

__device__ __forceinline__ ushort_t f2bf(float f) {
  union { float f; unsigned int u; } c; c.f = f;
  unsigned int r = c.u + 0x7FFFu + ((c.u >> 16) & 1u);
  return (ushort_t)(r >> 16);
}

// Async 16B global->LDS (lane-contiguous LDS dest required: base + lane*16).
__device__ __forceinline__ void async16(const ushort_t* g, ushort_t* l) {
  __builtin_amdgcn_global_load_lds(
      (const __attribute__((address_space(1))) unsigned int*)g,
      (__attribute__((address_space(3))) unsigned int*)l, 16, 0, 0);
}

// C[M,N] = A[M,K] (row-major bf16) x Bt[N,K] (row-major bf16), fp32 accum.
// BIASM: 0 none, 1 bias[m], 2 bias[n]  (bias fp32)
// POOLM: 0 none, 1 pool n-pairs (shfl, write n/2), 2 pool m-pairs (write m/2)
// OUTF32: write float instead of bf16.
template<int BIASM, int POOLM, bool OUTF32>
__global__ __launch_bounds__(256)
void gemm_bt(const ushort_t* __restrict__ A, long aStr,
             const ushort_t* __restrict__ B, long bStr,
             void* __restrict__ Cp, long cStr,
             int K, int lda, int ldb, int ldc,
             const float* __restrict__ bias, float scale)
{
  __shared__ ushort_t As[BM][BKK];
  __shared__ ushort_t Bs[BN][BKK];
  A += (long)blockIdx.z * aStr;
  B += (long)blockIdx.z * bStr;
  float* Cf = (float*)Cp + (OUTF32 ? (long)blockIdx.z * cStr : 0);
  ushort_t* Cb = (ushort_t*)Cp + (OUTF32 ? 0 : (long)blockIdx.z * cStr);
  const int m0 = blockIdx.y * BM;
  const int n0 = blockIdx.x * BN;
  const int tid = threadIdx.x;
  const int lane = tid & 63;
  const int wm = (tid >> 7) & 1;
  const int wn = (tid >> 6) & 1;
  const int ar = tid >> 3;         // staging row 0..31
  const int ac = (tid & 7) * 8;    // staging col (8 bf16 = 16B per thread)

  floatx4 acc[4][4];
#pragma unroll
  for (int i = 0; i < 4; ++i)
#pragma unroll
    for (int j = 0; j < 4; ++j)
#pragma unroll
      for (int r = 0; r < 4; ++r) acc[i][j][r] = 0.0f;

  const int q8 = (lane >> 4) * 8;
  const int l15 = lane & 15;

  const ushort_t* gA = &A[(long)(m0 + ar) * lda + ac];
  const ushort_t* gB = &B[(long)(n0 + ar) * ldb + ac];
  const long aRow32 = (long)32 * lda;
  const long bRow32 = (long)32 * ldb;

  for (int k0 = 0; k0 < K; k0 += BKK) {
#pragma unroll
    for (int p = 0; p < 4; ++p)
      async16(gA + p * aRow32 + k0, &As[p * 32 + ar][ac]);
#pragma unroll
    for (int p = 0; p < 4; ++p)
      async16(gB + p * bRow32 + k0, &Bs[p * 32 + ar][ac]);
    __syncthreads();
#pragma unroll
    for (int kk = 0; kk < 2; ++kk) {
      const int kr = kk * 32 + q8;
      bf16x8 af[4], bfr[4];
#pragma unroll
      for (int i = 0; i < 4; ++i) {
        af[i]  = *(const bf16x8*)(&As[wm * 64 + i * 16 + l15][kr]);
        bfr[i] = *(const bf16x8*)(&Bs[wn * 64 + i * 16 + l15][kr]);
      }
#pragma unroll
      for (int i = 0; i < 4; ++i)
#pragma unroll
        for (int j = 0; j < 4; ++j)
          acc[i][j] = __builtin_amdgcn_mfma_f32_16x16x32_bf16(af[i], bfr[j], acc[i][j], 0, 0, 0);
    }
    __syncthreads();
  }

#pragma unroll
  for (int i = 0; i < 4; ++i) {
    const int mbase = m0 + wm * 64 + i * 16 + (lane >> 4) * 4;
#pragma unroll
    for (int j = 0; j < 4; ++j) {
      const int n = n0 + wn * 64 + j * 16 + l15;
      float v[4];
#pragma unroll
      for (int r = 0; r < 4; ++r) {
        v[r] = acc[i][j][r] * scale;
        if (BIASM == 1) v[r] += bias[mbase + r];
      }
      if (BIASM == 2) {
        const float bn_ = bias[n];
#pragma unroll
        for (int r = 0; r < 4; ++r) v[r] += bn_;
      }
      if (POOLM == 0) {
#pragma unroll
        for (int r = 0; r < 4; ++r) {
          if (OUTF32) Cf[(long)(mbase + r) * ldc + n] = v[r];
          else        Cb[(long)(mbase + r) * ldc + n] = f2bf(v[r]);
        }
      } else if (POOLM == 1) {
#pragma unroll
        for (int r = 0; r < 4; ++r) {
          float o = __shfl_xor(v[r], 1);
          float w = fmaxf(v[r], o);
          if ((lane & 1) == 0) {
            if (OUTF32) Cf[(long)(mbase + r) * ldc + (n >> 1)] = w;
            else        Cb[(long)(mbase + r) * ldc + (n >> 1)] = f2bf(w);
          }
        }
      } else {  // POOLM == 2
        float w0 = fmaxf(v[0], v[1]);
        float w1 = fmaxf(v[2], v[3]);
        const int mh = mbase >> 1;
        if (OUTF32) {
          Cf[(long)mh * ldc + n] = w0;
          Cf[(long)(mh + 1) * ldc + n] = w1;
        } else {
          Cb[(long)mh * ldc + n] = f2bf(w0);
          Cb[(long)(mh + 1) * ldc + n] = f2bf(w1);
        }
      }
    }
  }
}

// dst[t][c] = bf16(src[c][t]) per batch (blockIdx.z). src: (Rr, Cl) fp32.
__global__ __launch_bounds__(256)
void transpose_f32_bf16(const float* __restrict__ src, ushort_t* __restrict__ dst,
                        int Rr, int Cl)
{
  __shared__ ushort_t tile[32][33];
  const long boff = (long)blockIdx.z * Rr * Cl;
  const int tx = threadIdx.x & 31;
  const int ty = threadIdx.x >> 5;
  const int c0 = blockIdx.x * 32;
  const int r0 = blockIdx.y * 32;
#pragma unroll
  for (int i = 0; i < 4; ++i) {
    int r = ty + i * 8;
    tile[r][tx] = f2bf(src[boff + (long)(r0 + r) * Cl + c0 + tx]);
  }
  __syncthreads();
#pragma unroll
  for (int i = 0; i < 4; ++i) {
    int r = ty + i * 8;
    dst[boff + (long)(c0 + r) * Rr + r0 + tx] = tile[tx][r];
  }
}

// Convert 4 equal-size fp32 weight buffers to contiguous bf16 regions.
__global__ __launch_bounds__(256)
void convert4(const float* __restrict__ a, const float* __restrict__ b,
              const float* __restrict__ c, const float* __restrict__ d,
              ushort_t* __restrict__ dst, int n)
{
  const float* srcs[4] = {a, b, c, d};
  const float* s = srcs[blockIdx.y];
  int i = blockIdx.x * 256 + threadIdx.x;
  if (i < n) dst[(long)blockIdx.y * n + i] = f2bf(s[i]);
}

// One block per channel c: mean/rstd over (B,T) of y (B,C,T) fp32.
__global__ __launch_bounds__(256)
void bn_stats(const float* __restrict__ y, float* __restrict__ stats)
{
  const int c = blockIdx.x;
  float s = 0.0f, s2 = 0.0f;
  for (int b = 0; b < 16; ++b) {
    const float* row = y + ((long)b * 1024 + c) * 2048;
    for (int t = threadIdx.x; t < 2048; t += 256) {
      float v = row[t];
      s += v; s2 += v * v;
    }
  }
#pragma unroll
  for (int o = 32; o > 0; o >>= 1) { s += __shfl_down(s, o); s2 += __shfl_down(s2, o); }
  __shared__ float red[8];
  const int lane = threadIdx.x & 63, w = threadIdx.x >> 6;
  if (lane == 0) { red[w] = s; red[4 + w] = s2; }
  __syncthreads();
  if (threadIdx.x == 0) {
    s = red[0] + red[1] + red[2] + red[3];
    s2 = red[4] + red[5] + red[6] + red[7];
    const float inv = 1.0f / (16.0f * 2048.0f);
    float mean = s * inv;
    float var = s2 * inv - mean * mean;
    stats[c * 2] = mean;
    stats[c * 2 + 1] = rsqrtf(var + 1e-5f);
  }
}

// In-place: y = gamma*(y-mean)*rstd + beta + x ; one block per (b,c) row.
__global__ __launch_bounds__(256)
void bn_apply(float* __restrict__ y, const float* __restrict__ x,
              const float* __restrict__ stats, const float* __restrict__ gamma,
              const float* __restrict__ beta)
{
  const int bc = blockIdx.x;
  const int c = bc & 1023;
  const long off = (long)bc * 2048;
  const float mean = stats[c * 2], rstd = stats[c * 2 + 1];
  const float g = gamma[c] * rstd;
  const float bt = beta[c];
  for (int t = threadIdx.x; t < 2048; t += 256) {
    y[off + t] = (y[off + t] - mean) * g + bt + x[off + t];
  }
}

extern "C" void kernel_launch(void* const* d_in, const int* in_sizes, int n_in,
                              void* d_out, int out_size, void* d_ws, size_t ws_size,
                              hipStream_t stream) {
  (void)in_sizes; (void)n_in; (void)out_size; (void)ws_size;
  const float* x  = (const float*)d_in[0];
  const float* Wq = (const float*)d_in[1];
  const float* bq = (const float*)d_in[2];
  const float* Wk = (const float*)d_in[3];
  const float* bk = (const float*)d_in[4];
  const float* Wv = (const float*)d_in[5];
  const float* bv = (const float*)d_in[6];
  const float* Wo = (const float*)d_in[7];
  const float* bo = (const float*)d_in[8];
  const float* gamma = (const float*)d_in[9];
  const float* beta  = (const float*)d_in[10];
  float* out = (float*)d_out;

  const int Cc = 1024, T = 2048, D = 512, S = 1024;

  // ws_size = 512 MiB (measured round 4): flat layout, no aliasing. ~239 MB used.
  ushort_t* ws   = (ushort_t*)d_ws;
  ushort_t* xT   = ws;                 // (B,T,C) 33,554,432
  ushort_t* Qt   = ws + 33554432;      // (B,T,D) 16,777,216
  ushort_t* Kt   = ws + 50331648;      // (B,S,D)  8,388,608
  ushort_t* V    = ws + 58720256;      // (B,D,S)  8,388,608
  ushort_t* attn = ws + 67108864;      // (B,T,S) 33,554,432
  ushort_t* out2 = ws + 100663296;     // (B,T,D) 16,777,216
  ushort_t* Wq_b = ws + 117440512;     //    524,288
  ushort_t* Wk_b = ws + 117964800;
  ushort_t* Wv_b = ws + 118489088;
  ushort_t* Wo_b = ws + 119013376;
  float*    stats = (float*)(ws + 119537664);  // 2048 floats

  dim3 blk(256);

  // 0. Weights fp32 -> bf16.
  convert4<<<dim3(2048, 4), blk, 0, stream>>>(Wq, Wk, Wv, Wo, Wq_b, D * Cc);

  // 1. xT = bf16(x^T) for all 16 batches.
  transpose_f32_bf16<<<dim3(T / 32, Cc / 32, 16), blk, 0, stream>>>(x, xT, Cc, T);

  // 2. Qt (T,D): M=T, N=D, K=C; bias bq by n.
  gemm_bt<2, 0, false><<<dim3(D / BN, T / BM, 16), blk, 0, stream>>>(
      xT, (long)T * Cc, Wq_b, 0, Qt, (long)T * D, Cc, Cc, Cc, D, bq, 1.0f);
  // 3. Kt (S,D): same GEMM, maxpool over time pairs (m), bias bk by n.
  gemm_bt<2, 2, false><<<dim3(D / BN, T / BM, 16), blk, 0, stream>>>(
      xT, (long)T * Cc, Wk_b, 0, Kt, (long)S * D, Cc, Cc, Cc, D, bk, 1.0f);
  // 4. V (D,S): M=D, N=T, K=C; maxpool over time pairs (n), bias bv by m.
  gemm_bt<1, 1, false><<<dim3(T / BN, D / BM, 16), blk, 0, stream>>>(
      Wv_b, 0, xT, (long)T * Cc, V, (long)D * S, Cc, Cc, Cc, S, bv, 1.0f);

  // 5. attn = (Qt x Kt^T)/T : M=T, N=S, K=D.
  gemm_bt<0, 0, false><<<dim3(S / BN, T / BM, 16), blk, 0, stream>>>(
      Qt, (long)T * D, Kt, (long)S * D, attn, (long)T * S,
      D, D, D, S, nullptr, 1.0f / 2048.0f);
  // 6. out2 = attn x V^T : M=T, N=D, K=S.
  gemm_bt<0, 0, false><<<dim3(D / BN, T / BM, 16), blk, 0, stream>>>(
      attn, (long)T * S, V, (long)D * S, out2, (long)T * D,
      S, S, S, D, nullptr, 1.0f);

  // 7. y = Wo x out2^T + bo -> d_out (fp32, (B,C,T)).
  gemm_bt<1, 0, true><<<dim3(T / BN, Cc / BM, 16), blk, 0, stream>>>(
      Wo_b, 0, out2, (long)T * D, out, (long)Cc * T, D, D, D, T, bo, 1.0f);

  // 8. BatchNorm (training stats, biased var) + residual, in place on d_out.
  bn_stats<<<dim3(1024), blk, 0, stream>>>(out, stats);
  bn_apply<<<dim3(16384), blk, 0, stream>>>(out, x, stats, gamma, beta);
}